// Round 8
// baseline (786.232 us; speedup 1.0000x reference)
//
#include <hip/hip_runtime.h>
#include <hip/hip_bf16.h>

typedef __bf16 bf16x8 __attribute__((ext_vector_type(8)));
typedef float  f32x4  __attribute__((ext_vector_type(4)));

#define MFMA16(a,b,c) __builtin_amdgcn_mfma_f32_16x16x32_bf16((a),(b),(c),0,0,0)

#if __has_builtin(__builtin_amdgcn_exp2f)
#define EXP2(x) __builtin_amdgcn_exp2f(x)
#else
#define EXP2(x) exp2f(x)
#endif
#define RCP(x) __builtin_amdgcn_rcpf(x)

#define KL  1.44269504088896340736f   /* log2(e)   */
#define K2L 2.88539008177792681472f   /* 2*log2(e) */

__device__ __forceinline__ bf16x8 cvt8(f32x4 a, f32x4 b){
  bf16x8 r;
  r[0]=(__bf16)a[0]; r[1]=(__bf16)a[1]; r[2]=(__bf16)a[2]; r[3]=(__bf16)a[3];
  r[4]=(__bf16)b[0]; r[5]=(__bf16)b[1]; r[6]=(__bf16)b[2]; r[7]=(__bf16)b[3];
  return r;
}
__device__ __forceinline__ f32x4 sp(float v){ return (f32x4){v,v,v,v}; }
__device__ __forceinline__ bf16x8 ld8(const float* p){
  return cvt8(*(const f32x4*)p, *(const f32x4*)(p+4));
}
// scaled load: 8 f32 -> *s -> bf16x8  (gate weights pre-scaled by log2e)
__device__ __forceinline__ bf16x8 ld8s(const float* p, float s){
  f32x4 a = *(const f32x4*)p, b = *(const f32x4*)(p+4);
  return cvt8(a*sp(s), b*sp(s));
}

// LSTM elementwise with PRE-SCALED gates (validated R3-R7, same absmax):
// 5 exp2 + 3 rcp; clamps keep saturation exact in fp32.
__device__ __forceinline__ float lstm_ew(float gi, float gf, float gg,
                                         float go, float& c){
  float Ef = EXP2(-gf);
  float Ei = EXP2(-gi);
  float gc = fminf(fmaxf(gg, -60.f), 60.f);
  float G  = EXP2(gc);
  float Rf = RCP(1.f + Ef);
  float Rig= RCP((1.f + Ei) * (1.f + G));
  c = c*Rf + (G - 1.f)*Rig;
  float Eo = EXP2(-go);
  float ch = fminf(fmaxf(c, -30.f), 30.f);
  float C2 = EXP2(ch * K2L);
  return (C2 - 1.f) * RCP((1.f + Eo) * (1.f + C2));
}

// lane^8 exchange within each 16-lane row: DPP row_ror:8 (VALU pipe, no LDS)
__device__ __forceinline__ float dppx8(float v){
  return __int_as_float(__builtin_amdgcn_update_dpp(
      0, __float_as_int(v), 0x128, 0xF, 0xF, true));
}
// lane^4 exchange: ds_swizzle xor-4 (decoder only)
__device__ __forceinline__ float swz4(float v){
  return __int_as_float(__builtin_amdgcn_ds_swizzle(__float_as_int(v), 0x101F));
}

// R8 = the measured-452us R4 kernel with ONE change: grp0's input path.
// Wemb is folded into L0's input weights (W' = eWih0 @ Wemb, K=32; bias' =
// eWih0@bemb + bih + bhh; numerically validated R3/R7 - same absmax), and the
// raw x fragment is kept in registers with R4's own PROVEN 2-slot-deep
// double-buffered prefetch (issue at slot I, consume at I+2 - the exact
// pattern R4 used for emb at 452us). This deletes, per grp0 wave per slot:
// 2 of 4 LDS b128 reads, 2 of 8 MFMAs, and the whole emb-MFMA/scatter side
// job on waves 0-3. grp1, EW math, schedule, strides, decoder: identical R4.
// (R3 had this fold but consumed x loaded IN the same slot -> every barrier's
// vmcnt(0) drained a fresh load -> regression. The 2-deep buffer fixes that.)
extern "C" __global__ void __launch_bounds__(1024, 4)
seq2seq_kernel(const float* __restrict__ X,
               const float* __restrict__ Wemb, const float* __restrict__ bemb,
               const float* __restrict__ eWih, const float* __restrict__ eWhh,
               const float* __restrict__ ebih, const float* __restrict__ ebhh,
               const float* __restrict__ dWih, const float* __restrict__ dWhh,
               const float* __restrict__ dbih, const float* __restrict__ dbhh,
               const float* __restrict__ Wreg, const float* __restrict__ breg,
               float* __restrict__ out)
{
  // XA[parity][row][136]: cols 0-63 = decoder input, 64-127 = h0.
  // h1 double-buffered.
  __shared__ __align__(16) __bf16 XA[2][8][136];
  __shared__ __align__(16) __bf16 H1s[2][8][72];

  const int tid  = (int)threadIdx.x;
  const int w    = tid >> 6;         // 0..15
  const int grp  = w >> 3;           // 0: layer0 group, 1: layer1 group
  const bool g0  = (grp == 0);
  const int wt   = w & 7;            // wave-in-group; units u0 = 8*wt
  const int lane = tid & 63;
  const int col  = lane & 15;
  const int quad = lane >> 4;
  const int r8   = col & 7;          // A real row (M=16 mirrors 8 rows)
  const int b0   = (int)blockIdx.x * 8;
  const int brow = b0 + r8;

  // fused-EW lane roles (encoder): cell = (row ewr, unit ewu)
  const bool hib = (col & 8) != 0;       // sr bit0
  const bool qhb = (quad & 2) != 0;      // sr bit1
  const int  ewr = 4*(quad & 1) + (hib ? 1 : 0) + (qhb ? 2 : 0);
  const int  ewu = 8*wt + (col & 7);

  for (int i = tid; i < 2*8*136; i += 1024) (&XA[0][0][0])[i]  = (__bf16)0.f;
  for (int i = tid; i < 2*8*72;  i += 1024) (&H1s[0][0][0])[i] = (__bf16)0.f;

  // ---- persistent fragments ----
  // gate-permuted col: n = 64*gate + unit, gate = 2*ti + (col>>3)
  // grp0: wf[ti*4+0] = W' x-frag (K=32, Wemb folded); wf[ti*4+2/3] = Whh.
  //       wf[ti*4+1] unused in encoder (decoder reloads all 8).
  // grp1: wf[ti*4+0..3] = [Wih | Whh] K=128 (identical to R4).
  bf16x8 wf[8];
  float  gb[2];
  if (g0){
#pragma unroll
    for (int ti=0; ti<2; ++ti){
      const int gate = 2*ti + (col>>3);
      const int n = 64*gate + 8*wt + (col&7);
      const float sc = (gate == 2) ? K2L : KL;
      // fold: W'[n][f] = sum_k eWih0[n][k]*Wemb[k][f];  bx = eWih0[n]@bemb
      f32x4 acL = sp(0.f), acH = sp(0.f);
      float bx = ebih[n] + ebhh[n];
      const float* wr_ = eWih + (size_t)n*64;
      for (int k=0; k<64; ++k){
        float a = wr_[k];
        bx += a * bemb[k];
        acL += sp(a) * *(const f32x4*)(Wemb + k*32 + quad*8);
        acH += sp(a) * *(const f32x4*)(Wemb + k*32 + quad*8 + 4);
      }
      wf[ti*4+0] = cvt8(acL*sp(sc), acH*sp(sc));
      wf[ti*4+2] = ld8s(eWhh + (size_t)n*64 +      quad*8, sc);
      wf[ti*4+3] = ld8s(eWhh + (size_t)n*64 + 32 + quad*8, sc);
      gb[ti] = bx * sc;
    }
  } else {
#pragma unroll
    for (int ti=0; ti<2; ++ti){
      const int gate = 2*ti + (col>>3);
      const int n = 256 + 64*gate + 8*wt + (col&7);
      const float sc = (gate == 2) ? K2L : KL;
      gb[ti] = (ebih[n] + ebhh[n]) * sc;
#pragma unroll
      for (int ks=0; ks<4; ++ks){
        const float* srcw = (ks < 2) ? eWih : eWhh;
        wf[ti*4+ks] = ld8s(srcw + (size_t)n*64 + (ks&1)*32 + quad*8, sc);
      }
    }
  }

  // x double-buffer (grp0): pair parity p holds x(t) with t&1 == p, held as
  // bf16x8. Issue at slot I for consumption at I+2 (R4's proven timing).
  const float* xb = X + (size_t)brow*512*32 + quad*8;
  bf16x8 xc0, xc1;
  if (g0){
    xc0 = cvt8(*(const f32x4*)(xb),    *(const f32x4*)(xb+4));    // x(0)
    xc1 = cvt8(*(const f32x4*)(xb+32), *(const f32x4*)(xb+36));   // x(1)
  }

  float cC = 0.f;   // grp0: c0 of cell (ewr,ewu); grp1: c1

  // in-register EW: gather (i,f,g,o) for this lane's cell via DPP xor-8.
  auto EWF = [&](f32x4 A0, f32x4 A1, float& c) -> float {
    float lo0 = qhb ? A0[2] : A0[0];
    float hi0 = qhb ? A0[3] : A0[1];
    float lo1 = qhb ? A1[2] : A1[0];
    float hi1 = qhb ? A1[3] : A1[1];
    float a0s = hib ? hi0 : lo0, a0x = hib ? lo0 : hi0;
    float a1s = hib ? hi1 : lo1, a1x = hib ? lo1 : hi1;
    float r0 = dppx8(a0x), r1 = dppx8(a1x);
    float gi = hib ? r0  : a0s;
    float gf = hib ? a0s : r0;
    float gg = hib ? r1  : a1s;
    float go = hib ? a1s : r1;
    return lstm_ew(gi, gf, gg, go, c);
  };

  // grp0 slot I: L0(I+1) from x(I+1)[regs] & h0(I)[LDS] -> h0(I+1);
  //              prefetch x(I+3) into the pair just consumed. 6 MFMAs.
  auto FUSED0 = [&](const int I){
    const int Px = (I+1)&1, Pr = I&1;
    bf16x8 axf = Px ? xc1 : xc0;
    { int tn = I+3; if (tn > 511) tn = 511;
      f32x4 na = *(const f32x4*)(xb + (size_t)tn*32);
      f32x4 nb = *(const f32x4*)(xb + (size_t)tn*32 + 4);
      if (Px) xc1 = cvt8(na, nb); else xc0 = cvt8(na, nb);
    }
    bf16x8 ah0 = *(const bf16x8*)&XA[Pr][r8][64 + quad*8];
    bf16x8 ah1 = *(const bf16x8*)&XA[Pr][r8][96 + quad*8];
    f32x4 A0 = sp(gb[0]), A1 = sp(gb[1]);
    A0=MFMA16(axf,wf[0],A0); A1=MFMA16(axf,wf[4],A1);
    A0=MFMA16(ah0,wf[2],A0); A1=MFMA16(ah0,wf[6],A1);
    A0=MFMA16(ah1,wf[3],A0); A1=MFMA16(ah1,wf[7],A1);
    XA[Px][ewr][64+ewu] = (__bf16)EWF(A0, A1, cC);
  };

  // grp1 slot I: L1(I) = [h0(I) | h1(I-1)] -> h1(I) at parity I&1 (= R4)
  auto FUSED1 = [&](const int I){
    const int Px = (I+1)&1, Pr = I&1;
    bf16x8 ah0 = *(const bf16x8*)&XA[Pr][r8][64 + quad*8];
    bf16x8 ah1 = *(const bf16x8*)&XA[Pr][r8][96 + quad*8];
    bf16x8 ag0 = *(const bf16x8*)&H1s[Px][r8][quad*8];
    bf16x8 ag1 = *(const bf16x8*)&H1s[Px][r8][32 + quad*8];
    f32x4 A0 = sp(gb[0]), A1 = sp(gb[1]);
    A0=MFMA16(ah0,wf[0],A0); A1=MFMA16(ah0,wf[4],A1);
    A0=MFMA16(ah1,wf[1],A0); A1=MFMA16(ah1,wf[5],A1);
    A0=MFMA16(ag0,wf[2],A0); A1=MFMA16(ag0,wf[6],A1);
    A0=MFMA16(ag1,wf[3],A0); A1=MFMA16(ag1,wf[7],A1);
    H1s[Pr][ewr][ewu] = (__bf16)EWF(A0, A1, cC);
  };

  __syncthreads();                 // zero-init visible

  // ---- prologue: L0(0) from x(0), h0(-1)=0 ----
  if (g0) FUSED0(-1);              // h0(0) -> parity 0; prefetch x(2)
  __syncthreads();

  // ---- steady encoder: slot I -> h0(I+1) & h1(I); ONE barrier/slot ----
#define SLOT(I) { if (g0) FUSED0(I); else FUSED1(I); __syncthreads(); }
  for (int ii=0; ii<255; ++ii){
    SLOT(2*ii)
    SLOT(2*ii+1)
  }
  SLOT(510)
#undef SLOT

  // ---- epilogue: h1(511) ----
  if (!g0) FUSED1(511);            // reads h0(511) (par 1), h1(510) (par 0)
  __syncthreads();

  // ================= decoder (verbatim R4) =================
  // init: XA[1] = [input=h1(511) | h0(511)] (h0(511) already at XA[1][64..])
  for (int idx = tid; idx < 8*64; idx += 1024){
    XA[1][idx>>6][idx&63] = H1s[1][idx>>6][idx&63];
  }
  // regression head (unscaled)
  bf16x8 wr0 = ld8(Wreg + (col&7)*64 +  0 + quad*8);
  bf16x8 wr1 = ld8(Wreg + (col&7)*64 + 32 + quad*8);
  const float rb = breg[col&7];
  // decoder: wave w owns 4 units (both layers), 16 gate-permuted cols:
  // col = [i(4) | f(4) | g(4) | o(4)], n = 64*(col>>2) + 4*w + (col&3)
  const int  gated = col >> 2;
  const float scd = (gated == 2) ? K2L : KL;
  float gbd[2];
#pragma unroll
  for (int l=0; l<2; ++l){
    const int n = 64*gated + 4*w + (col&3);
    gbd[l] = (dbih[l*256+n] + dbhh[l*256+n]) * scd;
#pragma unroll
    for (int ks=0; ks<4; ++ks){
      const float* srcw = (ks < 2) ? dWih : dWhh;
      wf[l*4+ks] = ld8s(srcw + ((size_t)(l*256+n))*64 + (ks&1)*32 + quad*8, scd);
    }
  }
  // decoder fused-EW lane roles: gate = col>>2; 2x redundancy, writer = even gate
  const bool b0d = (gated & 1) != 0;
  const bool b1d = (gated & 2) != 0;     // sr bit0
  const int  rd  = 4*(quad & 1) + (b1d ? 1 : 0) + (qhb ? 2 : 0);
  const int  udj = 4*w + (col & 3);
  float cD0 = 0.f, cD1 = 0.f;
  __syncthreads();

  // 4-gate gather: xor-4 (swz) for gate^1, xor-8 (DPP) for gate^2/^3
  auto EWD = [&](f32x4 B, float& c) -> float {
    float lo  = qhb ? B[2] : B[0];
    float hi2 = qhb ? B[3] : B[1];
    float a  = b1d ? hi2 : lo;           // own gate, elem sr
    float ax = b1d ? lo  : hi2;          // own gate, elem sr^1
    float pA = swz4(a);                  // gate^1 @ sr
    float pB = swz4(ax);                 // gate^1 @ sr^1
    float qA = dppx8(ax);                // gate^2 @ sr
    float qB = dppx8(pB);                // gate^3 @ sr
    float gi = b1d ? (b0d?qB:qA) : (b0d?pA:a);
    float gf = b1d ? (b0d?qA:qB) : (b0d?a:pA);
    float gg = b1d ? (b0d?pA:a) : (b0d?qB:qA);
    float go = b1d ? (b0d?a:pA) : (b0d?qA:qB);
    return lstm_ew(gi, gf, gg, go, c);
  };

  auto Ystore = [&](const int t){
    const int hp = t&1;
    f32x4 ya = sp(rb);
    bf16x8 y0 = *(const bf16x8*)&H1s[hp][r8][quad*8];
    bf16x8 y1 = *(const bf16x8*)&H1s[hp][r8][32 + quad*8];
    ya = MFMA16(y0, wr0, ya);
    ya = MFMA16(y1, wr1, ya);
    if (quad < 2 && col < 8){
#pragma unroll
      for (int r=0; r<4; ++r)
        out[((size_t)(b0 + quad*4 + r)*48 + t)*8 + col] = ya[r];
    }
  };

  // per step: 2 fused phases. h0/h1/input all parity-double-buffered.
#define DSTEP(T) {                                                         \
    const int P = (T)&1, Pm = P^1;                                         \
    {                                                                      \
      bf16x8 ax0 = *(const bf16x8*)&XA[Pm][r8][ 0 + quad*8];               \
      bf16x8 ax1 = *(const bf16x8*)&XA[Pm][r8][32 + quad*8];               \
      bf16x8 ah0 = *(const bf16x8*)&XA[Pm][r8][64 + quad*8];               \
      bf16x8 ah1 = *(const bf16x8*)&XA[Pm][r8][96 + quad*8];               \
      f32x4 B0 = sp(gbd[0]);                                               \
      B0=MFMA16(ax0,wf[0],B0); B0=MFMA16(ax1,wf[1],B0);                    \
      B0=MFMA16(ah0,wf[2],B0); B0=MFMA16(ah1,wf[3],B0);                    \
      float h = EWD(B0, cD0);                                              \
      if (!b0d) XA[P][rd][64+udj] = (__bf16)h;                             \
      if ((T) && w == 0) Ystore((T)-1);                                    \
    }                                                                      \
    __syncthreads();                                                       \
    {                                                                      \
      bf16x8 ah0 = *(const bf16x8*)&XA[P][r8][64 + quad*8];                \
      bf16x8 ah1 = *(const bf16x8*)&XA[P][r8][96 + quad*8];                \
      bf16x8 ag0 = *(const bf16x8*)&H1s[Pm][r8][ 0 + quad*8];              \
      bf16x8 ag1 = *(const bf16x8*)&H1s[Pm][r8][32 + quad*8];              \
      f32x4 B1 = sp(gbd[1]);                                               \
      B1=MFMA16(ah0,wf[4],B1); B1=MFMA16(ah1,wf[5],B1);                    \
      B1=MFMA16(ag0,wf[6],B1); B1=MFMA16(ag1,wf[7],B1);                    \
      float h = EWD(B1, cD1);                                              \
      if (!b0d){ H1s[P][rd][udj] = (__bf16)h; XA[P][rd][udj] = (__bf16)h; }\
    }                                                                      \
    __syncthreads();                                                       \
  }

  for (int tt=0; tt<24; ++tt){
    DSTEP(2*tt)
    DSTEP(2*tt+1)
  }
#undef DSTEP
  if (w == 0) Ystore(47);
}

extern "C" void kernel_launch(void* const* d_in, const int* in_sizes, int n_in,
                              void* d_out, int out_size, void* d_ws, size_t ws_size,
                              hipStream_t stream)
{
  (void)in_sizes; (void)n_in; (void)out_size; (void)d_ws; (void)ws_size;
  const float* X    = (const float*)d_in[0];
  const float* Wemb = (const float*)d_in[2];
  const float* bemb = (const float*)d_in[3];
  const float* eWih = (const float*)d_in[4];
  const float* eWhh = (const float*)d_in[5];
  const float* ebih = (const float*)d_in[6];
  const float* ebhh = (const float*)d_in[7];
  const float* dWih = (const float*)d_in[8];
  const float* dWhh = (const float*)d_in[9];
  const float* dbih = (const float*)d_in[10];
  const float* dbhh = (const float*)d_in[11];
  const float* Wreg = (const float*)d_in[12];
  const float* breg = (const float*)d_in[13];
  float* out = (float*)d_out;

  seq2seq_kernel<<<dim3(256), dim3(1024), 0, stream>>>(
      X, Wemb, bemb, eWih, eWhh, ebih, ebhh,
      dWih, dWhh, dbih, dbhh, Wreg, breg, out);
}

// Round 9
// 625.911 us; speedup vs baseline: 1.2561x; 1.2561x over previous
//
#include <hip/hip_runtime.h>
#include <hip/hip_bf16.h>

typedef __bf16 bf16x8 __attribute__((ext_vector_type(8)));
typedef float  f32x4  __attribute__((ext_vector_type(4)));

#define MFMA16(a,b,c) __builtin_amdgcn_mfma_f32_16x16x32_bf16((a),(b),(c),0,0,0)

#if __has_builtin(__builtin_amdgcn_exp2f)
#define EXP2(x) __builtin_amdgcn_exp2f(x)
#else
#define EXP2(x) exp2f(x)
#endif
#define RCP(x) __builtin_amdgcn_rcpf(x)

#define KL  1.44269504088896340736f   /* log2(e)   */
#define K2L 2.88539008177792681472f   /* 2*log2(e) */

__device__ __forceinline__ bf16x8 cvt8(f32x4 a, f32x4 b){
  bf16x8 r;
  r[0]=(__bf16)a[0]; r[1]=(__bf16)a[1]; r[2]=(__bf16)a[2]; r[3]=(__bf16)a[3];
  r[4]=(__bf16)b[0]; r[5]=(__bf16)b[1]; r[6]=(__bf16)b[2]; r[7]=(__bf16)b[3];
  return r;
}
__device__ __forceinline__ f32x4 sp(float v){ return (f32x4){v,v,v,v}; }
__device__ __forceinline__ bf16x8 ld8(const float* p){
  return cvt8(*(const f32x4*)p, *(const f32x4*)(p+4));
}
// scaled load: 8 f32 -> *s -> bf16x8  (gate weights pre-scaled by log2e)
__device__ __forceinline__ bf16x8 ld8s(const float* p, float s){
  f32x4 a = *(const f32x4*)p, b = *(const f32x4*)(p+4);
  return cvt8(a*sp(s), b*sp(s));
}

// LSTM elementwise with PRE-SCALED gates (validated R3-R8, same absmax):
// 5 exp2 + 3 rcp; clamps keep saturation exact in fp32.
__device__ __forceinline__ float lstm_ew(float gi, float gf, float gg,
                                         float go, float& c){
  float Ef = EXP2(-gf);
  float Ei = EXP2(-gi);
  float gc = fminf(fmaxf(gg, -60.f), 60.f);
  float G  = EXP2(gc);
  float Rf = RCP(1.f + Ef);
  float Rig= RCP((1.f + Ei) * (1.f + G));
  c = c*Rf + (G - 1.f)*Rig;
  float Eo = EXP2(-go);
  float ch = fminf(fmaxf(c, -30.f), 30.f);
  float C2 = EXP2(ch * K2L);
  return (C2 - 1.f) * RCP((1.f + Eo) * (1.f + C2));
}

// lane^8 exchange within each 16-lane row: DPP row_ror:8 (VALU pipe, no LDS)
__device__ __forceinline__ float dppx8(float v){
  return __int_as_float(__builtin_amdgcn_update_dpp(
      0, __float_as_int(v), 0x128, 0xF, 0xF, true));
}
// lane^1 exchange: DPP quad_perm [1,0,3,2] (VALU pipe, no LDS)
__device__ __forceinline__ unsigned dppx1(unsigned v){
  return (unsigned)__builtin_amdgcn_update_dpp(
      0, (int)v, 0xB1, 0xF, 0xF, true);
}
// lane^4 exchange: ds_swizzle xor-4 (decoder only)
__device__ __forceinline__ float swz4(float v){
  return __int_as_float(__builtin_amdgcn_ds_swizzle(__float_as_int(v), 0x101F));
}
// float -> bf16 bit pattern in low 16
__device__ __forceinline__ unsigned bfbits(float f){
  __bf16 b = (__bf16)f;
  return (unsigned)__builtin_bit_cast(unsigned short, b);
}

// R9 = the measured-452us R4 kernel with ONE change: every scattered bf16
// LDS store (encoder h0/h1, emb scatter, decoder h0/h1/feedback) is packed
// to a full ds_write_b32. At each site, lanes col and col^1 hold the two
// halves of the same LDS dword (row index ewr/rd is invariant under col->
// col^1; unit index flips bit 0) -> one DPP quad_perm exchange (VALU pipe)
// + even-col lane writes b32. Halves store-instr count and removes the
// same-dword sub-word collisions suspected to be the 4.0e7 conflict source.
// Values stored bit-identical; schedule/reads/parities byte-identical to R4.
extern "C" __global__ void __launch_bounds__(1024, 4)
seq2seq_kernel(const float* __restrict__ X,
               const float* __restrict__ Wemb, const float* __restrict__ bemb,
               const float* __restrict__ eWih, const float* __restrict__ eWhh,
               const float* __restrict__ ebih, const float* __restrict__ ebhh,
               const float* __restrict__ dWih, const float* __restrict__ dWhh,
               const float* __restrict__ dbih, const float* __restrict__ dbhh,
               const float* __restrict__ Wreg, const float* __restrict__ breg,
               float* __restrict__ out)
{
  // XA[parity][row][136]: cols 0-63 = x/input, 64-127 = h0. h1 double-buffered.
  __shared__ __align__(16) __bf16 XA[2][8][136];
  __shared__ __align__(16) __bf16 H1s[2][8][72];

  const int tid  = (int)threadIdx.x;
  const int w    = tid >> 6;         // 0..15
  const int grp  = w >> 3;           // 0: layer0 group, 1: layer1 group
  const bool g0  = (grp == 0);
  const int wt   = w & 7;            // wave-in-group; units u0 = 8*wt
  const int lane = tid & 63;
  const int col  = lane & 15;
  const int quad = lane >> 4;
  const int row8 = col & 7;          // A real row (M=16 mirrors 8 rows)
  const int b0   = (int)blockIdx.x * 8;
  const int brow = b0 + row8;

  // fused-EW lane roles (encoder): cell = (row ewr, unit ewu), elem index sr
  const bool hib = (col & 8) != 0;       // sr bit0
  const bool qhb = (quad & 2) != 0;      // sr bit1
  const int  ewr = 4*(quad & 1) + (hib ? 1 : 0) + (qhb ? 2 : 0);
  const bool wlo = (col & 1) == 0;       // packed-store writer lane
  const int  ewd = 4*wt + ((col & 7) >> 1);   // packed dword idx (enc)

  for (int i = tid; i < 2*8*136; i += 1024) (&XA[0][0][0])[i]  = (__bf16)0.f;
  for (int i = tid; i < 2*8*72;  i += 1024) (&H1s[0][0][0])[i] = (__bf16)0.f;

  // ---- persistent fragments: 2 tiles x 4 ksteps = 32 regs ----
  // gate-permuted col: n = 64*gate + unit, gate = 2*ti + (col>>3)
  bf16x8 wf[8];
  float  gb[2];
#pragma unroll
  for (int ti=0; ti<2; ++ti){
    const int gate = 2*ti + (col>>3);
    const int n = 64*gate + 8*wt + (col&7);
    const float sc = (gate == 2) ? K2L : KL;
    gb[ti] = (ebih[grp*256+n] + ebhh[grp*256+n]) * sc;
#pragma unroll
    for (int ks=0; ks<4; ++ks){
      const float* srcw = (ks < 2) ? eWih : eWhh;
      wf[ti*4+ks] = ld8s(srcw + ((size_t)(grp*256+n))*64 + (ks&1)*32 + quad*8, sc);
    }
  }

  // emb fragments: only waves 0-3 use them (emb itself stays UNSCALED;
  // the log2e scaling lives in the eWih fragments that consume it)
  const int ue = (w&3)*16 + col;
  bf16x8 wembf;
  float eb = 0.f;
  const float* xb = X + (size_t)brow*512*32 + quad*8;
  f32x4 pa0, pb0, pa1, pb1;
  if (w < 4){
    wembf = ld8(Wemb + ue*32 + quad*8);
    eb = bemb[ue];
    pa1 = *(const f32x4*)(xb+32); pb1 = *(const f32x4*)(xb+36);   // x(1)
    pa0 = *(const f32x4*)(xb+64); pb0 = *(const f32x4*)(xb+68);   // x(2)
  }

  float cC = 0.f;   // grp0: c0 of cell (ewr,ewu); grp1: c1

  // in-register EW: gather (i,f,g,o) for this lane's cell via DPP xor-8.
  auto EWF = [&](f32x4 A0, f32x4 A1, float& c) -> float {
    float lo0 = qhb ? A0[2] : A0[0];
    float hi0 = qhb ? A0[3] : A0[1];
    float lo1 = qhb ? A1[2] : A1[0];
    float hi1 = qhb ? A1[3] : A1[1];
    float a0s = hib ? hi0 : lo0, a0x = hib ? lo0 : hi0;
    float a1s = hib ? hi1 : lo1, a1x = hib ? lo1 : hi1;
    float r0 = dppx8(a0x), r1 = dppx8(a1x);
    float gi = hib ? r0  : a0s;
    float gf = hib ? a0s : r0;
    float gg = hib ? r1  : a1s;
    float go = hib ? a1s : r1;
    return lstm_ew(gi, gf, gg, go, c);
  };

  // packed emb scatter: lanes col/col^1 share dword ue>>1 of each row
  auto embStore = [&](const int s, f32x4 ea){
#pragma unroll
    for (int r=0; r<4; ++r){
      unsigned ebt = bfbits(ea[r]);
      unsigned epp = dppx1(ebt);
      if (quad < 2 && wlo)
        ((unsigned*)&XA[s][quad*4+r][0])[ue>>1] = ebt | (epp << 16);
    }
  };

  // grp0 slot I: gates+cells of L0(I+1) -> h0(I+1) at parity (I+1)&1;
  //             emb(I+2) -> XA[I&1].x (waves 0-3)
  auto FUSED0 = [&](const int I){
    const int Px = (I+1)&1, Pr = I&1;
    bf16x8 ax0 = *(const bf16x8*)&XA[Px][row8][ 0 + quad*8];
    bf16x8 ax1 = *(const bf16x8*)&XA[Px][row8][32 + quad*8];
    bf16x8 ah0 = *(const bf16x8*)&XA[Pr][row8][64 + quad*8];
    bf16x8 ah1 = *(const bf16x8*)&XA[Pr][row8][96 + quad*8];
    f32x4 A0 = sp(gb[0]), A1 = sp(gb[1]);
    A0=MFMA16(ax0,wf[0],A0); A1=MFMA16(ax0,wf[4],A1);
    A0=MFMA16(ax1,wf[1],A0); A1=MFMA16(ax1,wf[5],A1);
    A0=MFMA16(ah0,wf[2],A0); A1=MFMA16(ah0,wf[6],A1);
    A0=MFMA16(ah1,wf[3],A0); A1=MFMA16(ah1,wf[7],A1);
    if (I < 510 && w < 4){
      const int s = I&1;
      f32x4 xr0 = s ? pa1 : pa0, xr1 = s ? pb1 : pb0;
      f32x4 ea = MFMA16(cvt8(xr0,xr1), wembf, sp(eb));
      int tn = I+4; if (tn > 511) tn = 511;
      f32x4 na = *(const f32x4*)(xb + (size_t)tn*32);
      f32x4 nb = *(const f32x4*)(xb + (size_t)tn*32 + 4);
      if (s){ pa1=na; pb1=nb; } else { pa0=na; pb0=nb; }
      embStore(s, ea);
    }
    float h = EWF(A0, A1, cC);
    unsigned hb = bfbits(h);
    unsigned pp = dppx1(hb);
    if (wlo)
      ((unsigned*)&XA[Px][ewr][0])[32 + ewd] = hb | (pp << 16);
  };

  // grp1 slot I: L1(I) = [h0(I) | h1(I-1)] -> h1(I) at parity I&1
  auto FUSED1 = [&](const int I){
    const int Px = (I+1)&1, Pr = I&1;
    bf16x8 ah0 = *(const bf16x8*)&XA[Pr][row8][64 + quad*8];
    bf16x8 ah1 = *(const bf16x8*)&XA[Pr][row8][96 + quad*8];
    bf16x8 ag0 = *(const bf16x8*)&H1s[Px][row8][quad*8];
    bf16x8 ag1 = *(const bf16x8*)&H1s[Px][row8][32 + quad*8];
    f32x4 A0 = sp(gb[0]), A1 = sp(gb[1]);
    A0=MFMA16(ah0,wf[0],A0); A1=MFMA16(ah0,wf[4],A1);
    A0=MFMA16(ah1,wf[1],A0); A1=MFMA16(ah1,wf[5],A1);
    A0=MFMA16(ag0,wf[2],A0); A1=MFMA16(ag0,wf[6],A1);
    A0=MFMA16(ag1,wf[3],A0); A1=MFMA16(ag1,wf[7],A1);
    float h = EWF(A0, A1, cC);
    unsigned hb = bfbits(h);
    unsigned pp = dppx1(hb);
    if (wlo)
      ((unsigned*)&H1s[Pr][ewr][0])[ewd] = hb | (pp << 16);
  };

  __syncthreads();                 // zero-init visible

  // ---- prologue: emb(0), then h0(0) ----
  if (w < 4){
    f32x4 x0a = *(const f32x4*)xb, x0b = *(const f32x4*)(xb+4);
    f32x4 e0 = MFMA16(cvt8(x0a,x0b), wembf, sp(eb));
    embStore(0, e0);
  }
  __syncthreads();
  if (g0) FUSED0(-1);              // h0(0) -> parity 0; emb(1) -> XA[1].x
  __syncthreads();

  // ---- steady encoder: slot I -> h0(I+1) & h1(I); ONE barrier/slot ----
#define SLOT(I) { if (g0) FUSED0(I); else FUSED1(I); __syncthreads(); }
  for (int ii=0; ii<255; ++ii){
    SLOT(2*ii)
    SLOT(2*ii+1)
  }
  SLOT(510)
#undef SLOT

  // ---- epilogue: h1(511) ----
  if (!g0) FUSED1(511);            // reads h0(511) (par 1), h1(510) (par 0)
  __syncthreads();

  // ================= decoder =================
  // init: XA[1] = [input=h1(511) | h0(511)] (h0(511) already at XA[1][64..])
  for (int idx = tid; idx < 8*64; idx += 1024){
    XA[1][idx>>6][idx&63] = H1s[1][idx>>6][idx&63];
  }
  // regression head (unscaled)
  bf16x8 wr0 = ld8(Wreg + (col&7)*64 +  0 + quad*8);
  bf16x8 wr1 = ld8(Wreg + (col&7)*64 + 32 + quad*8);
  const float rb = breg[col&7];
  // decoder: wave w owns 4 units (both layers), 16 gate-permuted cols:
  // col = [i(4) | f(4) | g(4) | o(4)], n = 64*(col>>2) + 4*w + (col&3)
  const int  gated = col >> 2;
  const float scd = (gated == 2) ? K2L : KL;
  float gbd[2];
#pragma unroll
  for (int l=0; l<2; ++l){
    const int n = 64*gated + 4*w + (col&3);
    gbd[l] = (dbih[l*256+n] + dbhh[l*256+n]) * scd;
#pragma unroll
    for (int ks=0; ks<4; ++ks){
      const float* srcw = (ks < 2) ? dWih : dWhh;
      wf[l*4+ks] = ld8s(srcw + ((size_t)(l*256+n))*64 + (ks&1)*32 + quad*8, scd);
    }
  }
  // decoder fused-EW lane roles: gate = col>>2; 2x redundancy, writer = even gate
  const bool b0d = (gated & 1) != 0;
  const bool b1d = (gated & 2) != 0;     // sr bit0
  const int  rd  = 4*(quad & 1) + (b1d ? 1 : 0) + (qhb ? 2 : 0);
  const int  dwd = 2*w + ((col & 3) >> 1);     // packed dword idx (dec)
  float cD0 = 0.f, cD1 = 0.f;
  __syncthreads();

  // 4-gate gather: xor-4 (swz) for gate^1, xor-8 (DPP) for gate^2/^3
  auto EWD = [&](f32x4 B, float& c) -> float {
    float lo  = qhb ? B[2] : B[0];
    float hi2 = qhb ? B[3] : B[1];
    float a  = b1d ? hi2 : lo;           // own gate, elem sr
    float ax = b1d ? lo  : hi2;          // own gate, elem sr^1
    float pA = swz4(a);                  // gate^1 @ sr
    float pB = swz4(ax);                 // gate^1 @ sr^1
    float qA = dppx8(ax);                // gate^2 @ sr
    float qB = dppx8(pB);                // gate^3 @ sr
    float gi = b1d ? (b0d?qB:qA) : (b0d?pA:a);
    float gf = b1d ? (b0d?qA:qB) : (b0d?a:pA);
    float gg = b1d ? (b0d?pA:a) : (b0d?qB:qA);
    float go = b1d ? (b0d?a:pA) : (b0d?qA:qB);
    return lstm_ew(gi, gf, gg, go, c);
  };

  auto Ystore = [&](const int t){
    const int hp = t&1;
    f32x4 ya = sp(rb);
    bf16x8 y0 = *(const bf16x8*)&H1s[hp][row8][quad*8];
    bf16x8 y1 = *(const bf16x8*)&H1s[hp][row8][32 + quad*8];
    ya = MFMA16(y0, wr0, ya);
    ya = MFMA16(y1, wr1, ya);
    if (quad < 2 && col < 8){
#pragma unroll
      for (int r=0; r<4; ++r)
        out[((size_t)(b0 + quad*4 + r)*48 + t)*8 + col] = ya[r];
    }
  };

  // per step: 2 fused phases. h0/h1/input all parity-double-buffered.
  // Stores packed: lanes col/col^1 share a dword (gated/b1d/rd invariant
  // under col->col^1; udj flips bit 0); writer = even gate AND even col.
#define DSTEP(T) {                                                         \
    const int P = (T)&1, Pm = P^1;                                         \
    {                                                                      \
      bf16x8 ax0 = *(const bf16x8*)&XA[Pm][row8][ 0 + quad*8];             \
      bf16x8 ax1 = *(const bf16x8*)&XA[Pm][row8][32 + quad*8];             \
      bf16x8 ah0 = *(const bf16x8*)&XA[Pm][row8][64 + quad*8];             \
      bf16x8 ah1 = *(const bf16x8*)&XA[Pm][row8][96 + quad*8];             \
      f32x4 B0 = sp(gbd[0]);                                               \
      B0=MFMA16(ax0,wf[0],B0); B0=MFMA16(ax1,wf[1],B0);                    \
      B0=MFMA16(ah0,wf[2],B0); B0=MFMA16(ah1,wf[3],B0);                    \
      float h = EWD(B0, cD0);                                              \
      unsigned hb = bfbits(h), pp = dppx1(hb);                             \
      if (!b0d && wlo)                                                     \
        ((unsigned*)&XA[P][rd][0])[32 + dwd] = hb | (pp << 16);            \
      if ((T) && w == 0) Ystore((T)-1);                                    \
    }                                                                      \
    __syncthreads();                                                       \
    {                                                                      \
      bf16x8 ah0 = *(const bf16x8*)&XA[P][row8][64 + quad*8];              \
      bf16x8 ah1 = *(const bf16x8*)&XA[P][row8][96 + quad*8];              \
      bf16x8 ag0 = *(const bf16x8*)&H1s[Pm][row8][ 0 + quad*8];            \
      bf16x8 ag1 = *(const bf16x8*)&H1s[Pm][row8][32 + quad*8];            \
      f32x4 B1 = sp(gbd[1]);                                               \
      B1=MFMA16(ah0,wf[4],B1); B1=MFMA16(ah1,wf[5],B1);                    \
      B1=MFMA16(ag0,wf[6],B1); B1=MFMA16(ag1,wf[7],B1);                    \
      float h = EWD(B1, cD1);                                              \
      unsigned hb = bfbits(h), pp = dppx1(hb);                             \
      if (!b0d && wlo){                                                    \
        unsigned pk = hb | (pp << 16);                                     \
        ((unsigned*)&H1s[P][rd][0])[dwd] = pk;                             \
        ((unsigned*)&XA[P][rd][0])[dwd]  = pk;                             \
      }                                                                    \
    }                                                                      \
    __syncthreads();                                                       \
  }

  for (int tt=0; tt<24; ++tt){
    DSTEP(2*tt)
    DSTEP(2*tt+1)
  }
#undef DSTEP
  if (w == 0) Ystore(47);
}

extern "C" void kernel_launch(void* const* d_in, const int* in_sizes, int n_in,
                              void* d_out, int out_size, void* d_ws, size_t ws_size,
                              hipStream_t stream)
{
  (void)in_sizes; (void)n_in; (void)out_size; (void)d_ws; (void)ws_size;
  const float* X    = (const float*)d_in[0];
  const float* Wemb = (const float*)d_in[2];
  const float* bemb = (const float*)d_in[3];
  const float* eWih = (const float*)d_in[4];
  const float* eWhh = (const float*)d_in[5];
  const float* ebih = (const float*)d_in[6];
  const float* ebhh = (const float*)d_in[7];
  const float* dWih = (const float*)d_in[8];
  const float* dWhh = (const float*)d_in[9];
  const float* dbih = (const float*)d_in[10];
  const float* dbhh = (const float*)d_in[11];
  const float* Wreg = (const float*)d_in[12];
  const float* breg = (const float*)d_in[13];
  float* out = (float*)d_out;

  seq2seq_kernel<<<dim3(256), dim3(1024), 0, stream>>>(
      X, Wemb, bemb, eWih, eWhh, ebih, ebhh,
      dWih, dWhh, dbih, dbhh, Wreg, breg, out);
}